// Round 3
// baseline (254.429 us; speedup 1.0000x reference)
//
#include <hip/hip_runtime.h>

// ---------------------------------------------------------------------------
// HVIN: maxpool -> composite5x5 conv -> VI scan (32^2, redundant per pair) ->
//       upsample -> composite5x5 conv -> VI scan (64^2, split across a block
//       pair with per-step halo exchange) -> final conv + BN + dueling head
//
// Grid: 256 blocks x 1024 threads. Pair (b, b^8) lives on the SAME XCD
// (blockIdx % 8 round-robin) and handles image n = (b&7) + (b>>4)*8,
// half = (b>>3)&1 (rows [0,32) / [32,64)). Wave 0 of each block owns the
// boundary row pair, so the release-store flag (vmcnt drain) makes the halo
// visible without an extra barrier: ONE __syncthreads per VI step.
//
// ws float layout:
//   [0..49]     WeffO   [64..225]  GO    [256..305] WeffI   [320..481] GI
//   [512..521]  bn_sum  [528..537] bn_sumsq
//   [544..1823] q_pix[128][10]
//   ints [1824..2079]: flags[256]  (zeroed by k_precomp each launch)
//   [2176..]    halo[256 blocks][3 slots][64]   (stride 192)
// ---------------------------------------------------------------------------

#define NEG_BIG (-3.402823466e38f)
#define SCOPE_AGENT __HIP_MEMORY_SCOPE_AGENT

__global__ void k_precomp(const float* __restrict__ conv_h_w,
                          const float* __restrict__ conv_r_w,
                          const float* __restrict__ vi_h_w,
                          const float* __restrict__ vi_r_w,
                          float* __restrict__ ws) {
    __shared__ float sG[2][162];
    int t = threadIdx.x; // 512 threads
    if (t < 324) {
        int set = t / 162;      // 0 = outer, 1 = inner
        int e   = t % 162;
        int ax = e % 3;  int e1 = e / 3;
        int ay = e1 % 3; int e2 = e1 / 3;
        int i  = e2 % 2; int e3 = e2 / 2;
        int bx = e3 % 3; int by = e3 / 3;
        const float* Wh = set ? vi_h_w : conv_h_w;
        const float* Wr = set ? vi_r_w : conv_r_w;
        float acc = 0.f;
        for (int c = 0; c < 150; ++c)
            acc += Wr[(c*3+by)*3+bx] * Wh[((c*2+i)*3+ay)*3+ax];
        sG[set][e] = acc;
        ws[(set ? 320 : 64) + e] = acc;
    }
    if (t >= 480 && t < 512) ws[512 + (t - 480)] = 0.f;  // zero BN accumulators
    if (t < 256) ((int*)ws)[1824 + t] = 0;               // zero pair-sync flags
    __syncthreads();
    if (t < 100) {
        int set = t / 50;
        int e   = t % 50;
        int i  = e / 25;
        int oy = (e % 25) / 5;
        int ox = e % 5;
        float acc = 0.f;
        for (int by = 0; by < 3; ++by) {
            int ay = oy - by; if (ay < 0 || ay > 2) continue;
            for (int bx = 0; bx < 3; ++bx) {
                int ax = ox - bx; if (ax < 0 || ax > 2) continue;
                acc += sG[set][(((by*3+bx)*2+i)*3+ay)*3+ax];
            }
        }
        ws[(set ? 256 : 0) + e] = acc;
    }
}

__global__ __launch_bounds__(1024, 4) void k_main(
    const float* __restrict__ Xg,        // [128][2][64][64]
    const int*   __restrict__ S1,
    const int*   __restrict__ S2,
    const float* __restrict__ conv_q_ws, // [16][10][3][3][3]
    const float* __restrict__ vi_q_ws,   // [16][10][2][3][3]
    const float* __restrict__ ws,        // composites (read-only)
    float*       __restrict__ wsm)       // BN accum + qpix + flags + halo
{
    __shared__ float sX[2][64][64];      // full image (both halves need halo)
    __shared__ float sX1[2][32][32];
    __shared__ float sr1[34][34];        // ring-padded r1, later v1
    __shared__ float sva[34][34];
    __shared__ float svb[34][34];
    __shared__ float sm[34][66];         // rows: global gr0-1..gr0+32, ring-padded
    __shared__ float sr[34][66];
    __shared__ float sV0[34][66];
    __shared__ float sV1[34][66];
    __shared__ float sRed[10][2];

    const int bid  = blockIdx.x;
    const int half = (bid >> 3) & 1;
    const int n    = (bid & 7) | ((bid >> 4) << 3);  // pair (b, b^8): same XCD
    const int gr0  = half << 5;          // first own global row
    const int t    = threadIdx.x;

    int*   flagMine = (int*)wsm + 1824 + bid;
    int*   flagPart = (int*)wsm + 1824 + (bid ^ 8);
    float* ghMine   = wsm + 2176 + bid * 192;
    float* ghPart   = wsm + 2176 + (bid ^ 8) * 192;

    // ---- zero-init ring/halo arrays (rings are never written again) ----
    {
        float* z;
        z = &sr1[0][0];  for (int i = t; i < 1156; i += 1024) z[i] = 0.f;
        z = &sva[0][0];  for (int i = t; i < 1156; i += 1024) z[i] = 0.f;
        z = &svb[0][0];  for (int i = t; i < 1156; i += 1024) z[i] = 0.f;
        z = &sm[0][0];   for (int i = t; i < 2244; i += 1024) z[i] = 0.f;
        z = &sr[0][0];   for (int i = t; i < 2244; i += 1024) z[i] = 0.f;
        z = &sV0[0][0];  for (int i = t; i < 2244; i += 1024) z[i] = 0.f;
        z = &sV1[0][0];  for (int i = t; i < 2244; i += 1024) z[i] = 0.f;
    }
    // ---- P0: load full X (coalesced float4) ----
    {
        const float4* src = (const float4*)(Xg + (size_t)n * 8192);
        float4* dst = (float4*)&sX[0][0][0];
        dst[t] = src[t];
        dst[t + 1024] = src[t + 1024];
    }
    __syncthreads();

    // ---- P1: maxpool 2x2 -> sX1 ----
    for (int idx = t; idx < 2048; idx += 1024) {
        int c = idx >> 10;
        int y = (idx >> 5) & 31;
        int x = idx & 31;
        float a0 = sX[c][2*y][2*x],   a1 = sX[c][2*y][2*x+1];
        float a2 = sX[c][2*y+1][2*x], a3 = sX[c][2*y+1][2*x+1];
        sX1[c][y][x] = fmaxf(fmaxf(a0, a1), fmaxf(a2, a3));
    }
    __syncthreads();

    // ---- P2: r1 = composite 5x5 conv(X1) + border correction (redundant) ----
    {
        const float* WeffI = ws + 256;
        const float* GI    = ws + 320;
        int y = t >> 5, x = t & 31;
        float acc = 0.f;
        for (int i = 0; i < 2; ++i)
            for (int oy = 0; oy < 5; ++oy) {
                int yy = y + oy - 2; if (yy < 0 || yy >= 32) continue;
                for (int ox = 0; ox < 5; ++ox) {
                    int xx = x + ox - 2; if (xx < 0 || xx >= 32) continue;
                    acc += WeffI[i*25 + oy*5 + ox] * sX1[i][yy][xx];
                }
            }
        if (y == 0 || y == 31 || x == 0 || x == 31) {
            float corr = 0.f;
            for (int by = 0; by < 3; ++by)
                for (int bx = 0; bx < 3; ++bx) {
                    int qy = y + by - 1, qx = x + bx - 1;
                    if (qy >= 0 && qy < 32 && qx >= 0 && qx < 32) continue;
                    const float* Gb = GI + (by*3+bx)*18;
                    for (int i = 0; i < 2; ++i)
                        for (int ay = 0; ay < 3; ++ay) {
                            int yy2 = qy + ay - 1; if (yy2 < 0 || yy2 >= 32) continue;
                            for (int ax = 0; ax < 3; ++ax) {
                                int xx2 = qx + ax - 1; if (xx2 < 0 || xx2 >= 32) continue;
                                corr += Gb[i*9 + ay*3 + ax] * sX1[i][yy2][xx2];
                            }
                        }
                }
            acc -= corr;
        }
        sr1[1+y][1+x] = acc;
    }
    __syncthreads();

    // ---- P3: inner VI loop (16 steps, 32x32, redundant per pair) ----
    {
        const int iy = t >> 5, ix = t & 31;
        float pr[3][3];
        #pragma unroll
        for (int dy = 0; dy < 3; ++dy)
            #pragma unroll
            for (int dx = 0; dx < 3; ++dx)
                pr[dy][dx] = sr1[iy+dy][ix+dx];
        float s = 0.f;

        auto istep = [&](float (&VC)[34][34], float (&VN)[34][34], int K) {
            const float* wk = vi_q_ws + K * 180;
            float pv[3][3];
            #pragma unroll
            for (int dy = 0; dy < 3; ++dy)
                #pragma unroll
                for (int dx = 0; dx < 3; ++dx)
                    pv[dy][dx] = VC[iy+dy][ix+dx];
            float m = NEG_BIG;
            for (int ch = 0; ch < 10; ++ch) {
                const float* wc = wk + ch * 18;
                float q = 0.f;
                #pragma unroll
                for (int ky = 0; ky < 3; ++ky)
                    #pragma unroll
                    for (int kx = 0; kx < 3; ++kx)
                        q += wc[ky*3+kx] * pr[ky][kx] + wc[9+ky*3+kx] * pv[ky][kx];
                m = fmaxf(m, q);
            }
            VN[1+iy][1+ix] = m;
            s += m;
            __syncthreads();
        };
        for (int k2 = 0; k2 < 8; ++k2) {
            istep(sva, svb, 2*k2);
            istep(svb, sva, 2*k2+1);
        }
        sr1[1+iy][1+ix] = s * 0.25f;   // v1 overwrites r1
    }
    __syncthreads();

    // ---- P4+P5: m = upsample(v1), r = composite conv(X); rows gr0-1..gr0+32 ----
    {
        const float* WeffO = ws;
        const float* GO    = ws + 64;
        int c = t & 63;
        for (int ar = t >> 6; ar < 34; ar += 16) {
            int g = gr0 + ar - 1;
            if ((unsigned)g < 64u) {
                // bilinear upsample 32->64 at (g, c)
                int y0, y1; float wy0, wy1;
                if ((g & 1) == 0) { y1 = g >> 1; y0 = (y1 > 0) ? y1 - 1 : 0; wy1 = 0.75f; wy0 = 0.25f; }
                else              { y0 = g >> 1; y1 = (y0 < 31) ? y0 + 1 : 31; wy0 = 0.75f; wy1 = 0.25f; }
                int xa, xb; float wx0, wx1;
                if ((c & 1) == 0) { xb = c >> 1; xa = (xb > 0) ? xb - 1 : 0; wx1 = 0.75f; wx0 = 0.25f; }
                else              { xa = c >> 1; xb = (xa < 31) ? xa + 1 : 31; wx0 = 0.75f; wx1 = 0.25f; }
                sm[ar][1+c] = wy0 * (wx0 * sr1[1+y0][1+xa] + wx1 * sr1[1+y0][1+xb])
                            + wy1 * (wx0 * sr1[1+y1][1+xa] + wx1 * sr1[1+y1][1+xb]);
                // composite 5x5 conv of X at (g, c)
                float acc = 0.f;
                for (int i = 0; i < 2; ++i)
                    for (int oy = 0; oy < 5; ++oy) {
                        int yy = g + oy - 2; if (yy < 0 || yy >= 64) continue;
                        for (int ox = 0; ox < 5; ++ox) {
                            int xx = c + ox - 2; if (xx < 0 || xx >= 64) continue;
                            acc += WeffO[i*25 + oy*5 + ox] * sX[i][yy][xx];
                        }
                    }
                if (g == 0 || g == 63 || c == 0 || c == 63) {
                    float corr = 0.f;
                    for (int by = 0; by < 3; ++by)
                        for (int bx = 0; bx < 3; ++bx) {
                            int qy = g + by - 1, qx = c + bx - 1;
                            if (qy >= 0 && qy < 64 && qx >= 0 && qx < 64) continue;
                            const float* Gb = GO + (by*3+bx)*18;
                            for (int i = 0; i < 2; ++i)
                                for (int ay = 0; ay < 3; ++ay) {
                                    int yy2 = qy + ay - 1; if (yy2 < 0 || yy2 >= 64) continue;
                                    for (int ax = 0; ax < 3; ++ax) {
                                        int xx2 = qx + ax - 1; if (xx2 < 0 || xx2 >= 64) continue;
                                        corr += Gb[i*9 + ay*3 + ax] * sX[i][yy2][xx2];
                                    }
                                }
                        }
                    acc -= corr;
                }
                sr[ar][1+c] = acc;
            }
        }
    }
    __syncthreads();

    // ---- P6: outer VI loop. Wave 0 owns the boundary row pair. ----
    const int rp = t >> 6;                       // wave id
    const int pp = half ? rp : (15 - rp);        // local row-pair index
    const int c  = t & 63;
    const int recvRow = half ? 0 : 33;           // array row holding partner halo

    float pm[4][3], prr[4][3];
    #pragma unroll
    for (int dy = 0; dy < 4; ++dy)
        #pragma unroll
        for (int dx = 0; dx < 3; ++dx) {
            pm[dy][dx]  = sm[2*pp+dy][c+dx];
            prr[dy][dx] = sr[2*pp+dy][c+dx];
        }

    float s0 = 0.f, s1 = 0.f;

    auto ostep = [&](float (&VC)[34][66], float (&VN)[34][66], int K) {
        const float* wk = conv_q_ws + K * 270;
        float pv[4][3];
        #pragma unroll
        for (int dy = 0; dy < 4; ++dy)
            #pragma unroll
            for (int dx = 0; dx < 3; ++dx)
                pv[dy][dx] = VC[2*pp+dy][c+dx];
        float vm0 = NEG_BIG, vm1 = NEG_BIG;
        for (int ch = 0; ch < 10; ++ch) {
            const float* wc = wk + ch * 27;
            float q0 = 0.f, q1 = 0.f;
            #pragma unroll
            for (int ky = 0; ky < 3; ++ky)
                #pragma unroll
                for (int kx = 0; kx < 3; ++kx) {
                    float wm = wc[ky*3+kx];
                    float wr = wc[9  + ky*3+kx];
                    float wv = wc[18 + ky*3+kx];
                    q0 += wm * pm[ky][kx]   + wr * prr[ky][kx]   + wv * pv[ky][kx];
                    q1 += wm * pm[ky+1][kx] + wr * prr[ky+1][kx] + wv * pv[ky+1][kx];
                }
            vm0 = fmaxf(vm0, q0);
            vm1 = fmaxf(vm1, q1);
        }
        VN[1+2*pp][1+c] = vm0;
        VN[2+2*pp][1+c] = vm1;
        s0 += vm0;
        s1 += vm1;
        if (K < 15 && rp == 0) {
            // wave 0 holds the boundary row: half0 -> its row 31 (vm1),
            // half1 -> its row 32 (vm0).
            __hip_atomic_store(ghMine + (K & 1) * 64 + c, half ? vm0 : vm1,
                               __ATOMIC_RELAXED, SCOPE_AGENT);
            if (t == 0) {
                // release drains this wave's halo stores (vmcnt) before flag
                __hip_atomic_store(flagMine, K + 1, __ATOMIC_RELEASE, SCOPE_AGENT);
                int spins = 0;
                while (__hip_atomic_load(flagPart, __ATOMIC_ACQUIRE, SCOPE_AGENT) < K + 1)
                    if (++spins > (1 << 27)) break;   // safety valve
            }
            float hv = __hip_atomic_load(ghPart + (K & 1) * 64 + t,
                                         __ATOMIC_RELAXED, SCOPE_AGENT);
            VN[recvRow][1+t] = hv;
        }
        __syncthreads();
    };

    for (int k2 = 0; k2 < 8; ++k2) {
        ostep(sV0, sV1, 2*k2);
        ostep(sV1, sV0, 2*k2+1);
    }

    // ---- vbar = sum/16 into sV1; exchange its halo (slot 2, flag 16) ----
    float vb0 = s0 * 0.0625f, vb1 = s1 * 0.0625f;
    sV1[1+2*pp][1+c] = vb0;
    sV1[2+2*pp][1+c] = vb1;
    if (rp == 0) {
        __hip_atomic_store(ghMine + 128 + c, half ? vb0 : vb1,
                           __ATOMIC_RELAXED, SCOPE_AGENT);
        if (t == 0) {
            __hip_atomic_store(flagMine, 16, __ATOMIC_RELEASE, SCOPE_AGENT);
            int spins = 0;
            while (__hip_atomic_load(flagPart, __ATOMIC_ACQUIRE, SCOPE_AGENT) < 16)
                if (++spins > (1 << 27)) break;
        }
        float hv = __hip_atomic_load(ghPart + 128 + t, __ATOMIC_RELAXED, SCOPE_AGENT);
        sV1[recvRow][1+t] = hv;
    }
    if (t >= 64 && t < 84) ((float*)sRed)[t - 64] = 0.f;
    __syncthreads();

    // ---- P7: final conv (w15) on {m, r, vbar} + BN stats + (S1,S2) pick ----
    {
        const float* wk = conv_q_ws + 15 * 270;
        float pv[4][3];
        #pragma unroll
        for (int dy = 0; dy < 4; ++dy)
            #pragma unroll
            for (int dx = 0; dx < 3; ++dx)
                pv[dy][dx] = sV1[2*pp+dy][c+dx];
        int sy = S1[n], sx = S2[n];
        int g0 = gr0 + 2*pp, g1 = g0 + 1;
        float* qpix = wsm + 544 + n * 10;
        for (int ch = 0; ch < 10; ++ch) {
            const float* wc = wk + ch * 27;
            float q0 = 0.f, q1 = 0.f;
            #pragma unroll
            for (int ky = 0; ky < 3; ++ky)
                #pragma unroll
                for (int kx = 0; kx < 3; ++kx) {
                    float wm = wc[ky*3+kx];
                    float wr = wc[9  + ky*3+kx];
                    float wv = wc[18 + ky*3+kx];
                    q0 += wm * pm[ky][kx]   + wr * prr[ky][kx]   + wv * pv[ky][kx];
                    q1 += wm * pm[ky+1][kx] + wr * prr[ky+1][kx] + wv * pv[ky+1][kx];
                }
            if (c == sx) {
                if (g0 == sy) qpix[ch] = q0;
                if (g1 == sy) qpix[ch] = q1;
            }
            float ls = q0 + q1, lq = q0*q0 + q1*q1;
            #pragma unroll
            for (int off = 32; off > 0; off >>= 1) {
                ls += __shfl_down(ls, off);
                lq += __shfl_down(lq, off);
            }
            if ((t & 63) == 0) {
                atomicAdd(&sRed[ch][0], ls);
                atomicAdd(&sRed[ch][1], lq);
            }
        }
        __syncthreads();
        if (t < 10) {
            atomicAdd(wsm + 512 + t, sRed[t][0]);
            atomicAdd(wsm + 528 + t, sRed[t][1]);
        }
    }
}

__global__ void k_final(const float* __restrict__ ws,
                        const float* __restrict__ gamma,
                        const float* __restrict__ beta,
                        const float* __restrict__ w1,
                        const float* __restrict__ w2,
                        float* __restrict__ out) {
    int n = threadIdx.x;
    if (n >= 128) return;
    const float inv = 1.f / 524288.f;
    float qn[10];
    for (int c = 0; c < 10; ++c) {
        float mean = ws[512 + c] * inv;
        float var  = ws[528 + c] * inv - mean * mean;
        float q    = ws[544 + n * 10 + c];
        qn[c] = (q - mean) * rsqrtf(var + 1e-5f) * gamma[c] + beta[c];
    }
    float a = 0.f;
    for (int c = 0; c < 10; ++c) a += qn[c] * w1[c];
    a = fmaxf(a, 0.f);
    float b[8], mb = 0.f;
    for (int j = 0; j < 8; ++j) {
        float bj = 0.f;
        for (int c = 0; c < 10; ++c) bj += qn[c] * w2[j * 10 + c];
        bj = fmaxf(bj, 0.f);
        b[j] = bj;
        mb += bj;
    }
    mb *= 0.125f;
    for (int j = 0; j < 8; ++j) out[n * 8 + j] = a + b[j] - mb;
}

extern "C" void kernel_launch(void* const* d_in, const int* in_sizes, int n_in,
                              void* d_out, int out_size, void* d_ws, size_t ws_size,
                              hipStream_t stream) {
    const float* X         = (const float*)d_in[0];
    const int*   S1        = (const int*)  d_in[1];
    const int*   S2        = (const int*)  d_in[2];
    const float* conv_h_w  = (const float*)d_in[3];
    const float* conv_r_w  = (const float*)d_in[4];
    const float* conv_q_ws = (const float*)d_in[5];
    const float* bn_gamma  = (const float*)d_in[6];
    const float* bn_beta   = (const float*)d_in[7];
    const float* duel_w1   = (const float*)d_in[8];
    const float* duel_w2   = (const float*)d_in[9];
    const float* vi_h_w    = (const float*)d_in[10];
    const float* vi_r_w    = (const float*)d_in[11];
    const float* vi_q_ws   = (const float*)d_in[12];
    float* ws = (float*)d_ws;

    k_precomp<<<1, 512, 0, stream>>>(conv_h_w, conv_r_w, vi_h_w, vi_r_w, ws);
    k_main<<<256, 1024, 0, stream>>>(X, S1, S2, conv_q_ws, vi_q_ws, ws, ws);
    k_final<<<1, 128, 0, stream>>>(ws, bn_gamma, bn_beta, duel_w1, duel_w2, (float*)d_out);
}